// Round 1
// baseline (383.869 us; speedup 1.0000x reference)
//
#include <hip/hip_runtime.h>
#include <hip/hip_bf16.h>

// QuadConv: out[N,64] = gather(features[N,32], neigh_idx[N,9] -> [N,288]) @ W.T + b
// N=500000, C_IN=32, C_OUT=64, K=9.  idx==-1 -> zero row.
//
// Strategy: 64 nodes/block, 256 threads (4 waves).
//   Phase 1: gather 576 rows (64 nodes x 9 neighbors) of 32 f32 -> bf16 into LDS
//            A[64][296]  (288 + 8 pad bf16; 592-byte rows, 16B aligned).
//   Phase 2: each wave computes a 32-node x 32-col tile:
//            18 K-steps of v_mfma_f32_32x32x16_bf16, W-fragments held in VGPRs.

typedef __bf16 bf16x8 __attribute__((ext_vector_type(8)));
typedef float f32x16 __attribute__((ext_vector_type(16)));

#define NPB   64      // nodes per block
#define PITCH 296     // bf16 elements per LDS row (288 + 8 pad) -> 592 B, 16B-aligned

__global__ __launch_bounds__(256) void quadconv_kernel(
    const float* __restrict__ feat,   // [N,32] f32
    const int*   __restrict__ nidx,   // [N,9]  i32, -1 = missing
    const float* __restrict__ Wm,     // [64,288] f32
    const float* __restrict__ bias,   // [64] f32
    float*       __restrict__ out,    // [N,64] f32
    int N)
{
    __shared__ __bf16 A[NPB][PITCH];

    const int tid  = threadIdx.x;
    const int lane = tid & 63;
    const int w    = tid >> 6;                    // wave 0..3
    const long long base = (long long)blockIdx.x * NPB;

    // ---------------- Phase 1: gather -> LDS (bf16) ----------------
    // 576 rows total; 4 threads per row, each handles 8 floats (two float4).
    const int q = tid & 3;                        // which float8 chunk of the row
    #pragma unroll 3
    for (int it = 0; it < 9; ++it) {
        int r    = (tid >> 2) + it * 64;          // row id 0..575
        int node = r / 9;                         // local node 0..63
        int j    = r - node * 9;                  // neighbor 0..8
        long long g = base + node;
        int idx = -1;
        if (g < (long long)N) idx = nidx[g * 9 + j];
        float4 f0 = make_float4(0.f, 0.f, 0.f, 0.f);
        float4 f1 = make_float4(0.f, 0.f, 0.f, 0.f);
        if (idx >= 0) {
            const float* sp = feat + (long long)idx * 32 + q * 8;
            f0 = *(const float4*)(sp);
            f1 = *(const float4*)(sp + 4);
        }
        bf16x8 v;
        v[0] = (__bf16)f0.x; v[1] = (__bf16)f0.y; v[2] = (__bf16)f0.z; v[3] = (__bf16)f0.w;
        v[4] = (__bf16)f1.x; v[5] = (__bf16)f1.y; v[6] = (__bf16)f1.z; v[7] = (__bf16)f1.w;
        *(bf16x8*)&A[node][j * 32 + q * 8] = v;
    }

    // ---------------- W fragments -> registers (overlap with barrier) ----------
    // Wave w: cols (w&1)*32 .. +31, nodes (w>>1)*32 .. +31.
    // B[k][n] = W[n][k]; lane holds B[k0+i][lane&31], k0 = kk*16 + (lane>>5)*8.
    const int colBase = (w & 1) * 32;
    const int col     = colBase + (lane & 31);
    const int khalf   = (lane >> 5) * 8;
    bf16x8 bw[18];
    #pragma unroll
    for (int kk = 0; kk < 18; ++kk) {
        const float* wp = Wm + col * 288 + kk * 16 + khalf;
        float4 w0 = *(const float4*)(wp);
        float4 w1 = *(const float4*)(wp + 4);
        bf16x8 v;
        v[0] = (__bf16)w0.x; v[1] = (__bf16)w0.y; v[2] = (__bf16)w0.z; v[3] = (__bf16)w0.w;
        v[4] = (__bf16)w1.x; v[5] = (__bf16)w1.y; v[6] = (__bf16)w1.z; v[7] = (__bf16)w1.w;
        bw[kk] = v;
    }
    const float bv = bias[col];

    __syncthreads();

    // ---------------- Phase 2: MFMA ----------------
    const int nodeOff = (w >> 1) * 32;
    const int arow    = nodeOff + (lane & 31);
    f32x16 acc;
    #pragma unroll
    for (int i = 0; i < 16; ++i) acc[i] = 0.0f;

    #pragma unroll
    for (int kk = 0; kk < 18; ++kk) {
        bf16x8 a = *(bf16x8*)&A[arow][kk * 16 + khalf];
        acc = __builtin_amdgcn_mfma_f32_32x32x16_bf16(a, bw[kk], acc, 0, 0, 0);
    }

    // ---------------- store ----------------
    // D[m][n]: n = lane&31 (=col-colBase), m = (reg&3) + 4*(lane>>5) + 8*(reg>>2)
    const int hi = lane >> 5;
    #pragma unroll
    for (int reg = 0; reg < 16; ++reg) {
        int m = (reg & 3) + 4 * hi + 8 * (reg >> 2);
        long long node = base + nodeOff + m;
        if (node < (long long)N) {
            out[node * 64 + col] = acc[reg] + bv;
        }
    }
}

extern "C" void kernel_launch(void* const* d_in, const int* in_sizes, int n_in,
                              void* d_out, int out_size, void* d_ws, size_t ws_size,
                              hipStream_t stream) {
    const float* feat = (const float*)d_in[0];
    const int*   nidx = (const int*)d_in[1];
    const float* Wm   = (const float*)d_in[2];
    const float* bias = (const float*)d_in[3];
    float*       out  = (float*)d_out;

    int N = in_sizes[0] / 32;                 // features is [N,32]
    int grid = (N + NPB - 1) / NPB;
    quadconv_kernel<<<grid, 256, 0, stream>>>(feat, nidx, Wm, bias, out, N);
}